// Round 1
// baseline (43989.102 us; speedup 1.0000x reference)
//
#include <hip/hip_runtime.h>
#include <cstddef>
#include <cstdint>

#define NB 32     // batch
#define HD 512    // hidden
#define GD 2048   // 4*hidden

__device__ __forceinline__ float sigf(float x)   { return 1.0f / (1.0f + __expf(-x)); }
__device__ __forceinline__ float tanhf_(float x) { return 2.0f / (1.0f + __expf(-2.0f * x)) - 1.0f; }

#define FMA16_BLOCK \
    acc[0][0] = fmaf(a4.x, b4.x, acc[0][0]); \
    acc[0][1] = fmaf(a4.x, b4.y, acc[0][1]); \
    acc[0][2] = fmaf(a4.x, b4.z, acc[0][2]); \
    acc[0][3] = fmaf(a4.x, b4.w, acc[0][3]); \
    acc[1][0] = fmaf(a4.y, b4.x, acc[1][0]); \
    acc[1][1] = fmaf(a4.y, b4.y, acc[1][1]); \
    acc[1][2] = fmaf(a4.y, b4.z, acc[1][2]); \
    acc[1][3] = fmaf(a4.y, b4.w, acc[1][3]); \
    acc[2][0] = fmaf(a4.z, b4.x, acc[2][0]); \
    acc[2][1] = fmaf(a4.z, b4.y, acc[2][1]); \
    acc[2][2] = fmaf(a4.z, b4.z, acc[2][2]); \
    acc[2][3] = fmaf(a4.z, b4.w, acc[2][3]); \
    acc[3][0] = fmaf(a4.w, b4.x, acc[3][0]); \
    acc[3][1] = fmaf(a4.w, b4.y, acc[3][1]); \
    acc[3][2] = fmaf(a4.w, b4.z, acc[3][2]); \
    acc[3][3] = fmaf(a4.w, b4.w, acc[3][3]);

// xg[b][tc][n] = sum_k A[b, t0+tc, k] * Wih[n, k] + bih[n] + bhh[n]
// A: (B, T, HD) row-major. W: (GD, HD) row-major (NT gemm). out: (B, Tc, GD).
__global__ __launch_bounds__(256) void gemm_xg(
    const float* __restrict__ A, int T, int t0, int tc_bits,
    const float* __restrict__ W,
    const float* __restrict__ bih, const float* __restrict__ bhh,
    float* __restrict__ out)
{
    __shared__ __align__(16) float As[16][68];
    __shared__ __align__(16) float Bs[16][68];
    const int tid = threadIdx.x;
    const int tx = tid & 15, ty = tid >> 4;
    const int m0 = blockIdx.x << 6, n0 = blockIdx.y << 6;
    const int lr = tid >> 2;
    const int lk = (tid & 3) << 2;
    const int r  = m0 + lr;
    const int b  = r >> tc_bits;
    const int tt = t0 + (r & ((1 << tc_bits) - 1));
    const float* aRow = A + (((size_t)b * T + tt) << 9) + lk;
    const float* wRow = W + (((size_t)(n0 + lr)) << 9) + lk;
    float acc[4][4] = {};
    for (int k0 = 0; k0 < HD; k0 += 16) {
        const float4 av = *(const float4*)(aRow + k0);
        const float4 wv = *(const float4*)(wRow + k0);
        As[lk][lr] = av.x; As[lk + 1][lr] = av.y; As[lk + 2][lr] = av.z; As[lk + 3][lr] = av.w;
        Bs[lk][lr] = wv.x; Bs[lk + 1][lr] = wv.y; Bs[lk + 2][lr] = wv.z; Bs[lk + 3][lr] = wv.w;
        __syncthreads();
#pragma unroll
        for (int k = 0; k < 16; ++k) {
            const float4 a4 = *(const float4*)&As[k][ty << 2];
            const float4 b4 = *(const float4*)&Bs[k][tx << 2];
            FMA16_BLOCK
        }
        __syncthreads();
    }
#pragma unroll
    for (int i = 0; i < 4; ++i) {
        const int rr = m0 + (ty << 2) + i;
#pragma unroll
        for (int j = 0; j < 4; ++j) {
            const int nn = n0 + (tx << 2) + j;
            out[((size_t)rr << 11) + nn] = acc[i][j] + bih[nn] + bhh[nn];
        }
    }
}

// Upsample: dst[b, t*U+uu, h] = sum_k A[b,t,k]*W[k, uu*512+h] + bias[uu*512+h] + xnext[...]
// A: (B, T, HD) contiguous. W: (HD, N) row-major (NN gemm), N = U*512.
__global__ __launch_bounds__(256) void gemm_up(
    const float* __restrict__ A,
    const float* __restrict__ W, int N,
    const float* __restrict__ bias,
    const float* __restrict__ xnext,
    float* __restrict__ dst, int t_bits, int u_bits)
{
    __shared__ __align__(16) float As[16][68];
    __shared__ __align__(16) float Bs[16][68];
    const int tid = threadIdx.x;
    const int tx = tid & 15, ty = tid >> 4;
    const int m0 = blockIdx.x << 6, n0 = blockIdx.y << 6;
    const int lr = tid >> 2, lk = (tid & 3) << 2;
    const float* aRow = A + (((size_t)(m0 + lr)) << 9) + lk;
    const int wk = tid >> 4, wn = (tid & 15) << 2;
    float acc[4][4] = {};
    for (int k0 = 0; k0 < HD; k0 += 16) {
        const float4 av = *(const float4*)(aRow + k0);
        const float4 wv = *(const float4*)(W + (size_t)(k0 + wk) * N + n0 + wn);
        As[lk][lr] = av.x; As[lk + 1][lr] = av.y; As[lk + 2][lr] = av.z; As[lk + 3][lr] = av.w;
        *(float4*)&Bs[wk][wn] = wv;
        __syncthreads();
#pragma unroll
        for (int k = 0; k < 16; ++k) {
            const float4 a4 = *(const float4*)&As[k][ty << 2];
            const float4 b4 = *(const float4*)&Bs[k][tx << 2];
            FMA16_BLOCK
        }
        __syncthreads();
    }
    const int T_1 = (1 << t_bits) - 1;
#pragma unroll
    for (int i = 0; i < 4; ++i) {
        const int rr = m0 + (ty << 2) + i;
        const int bb = rr >> t_bits, tt = rr & T_1;
#pragma unroll
        for (int j = 0; j < 4; ++j) {
            const int nn = n0 + (tx << 2) + j;
            const int uu = nn >> 9, hh = nn & 511;
            const size_t di = (((size_t)((((bb << t_bits) + tt) << u_bits) + uu)) << 9) + hh;
            dst[di] = acc[i][j] + bias[nn] + xnext[di];
        }
    }
}

// One recurrence step. Grid = 256 blocks; block owns 2 hidden indices j (8 gate rows)
// for all 32 batch items. h_{t-1} read from previous step's output (kernel-boundary sync).
__global__ __launch_bounds__(256) void lstm_step(
    const float* __restrict__ xgs, int xgb,          // xg + s*GD; per-b stride Tc*GD
    const float* __restrict__ Whh,                   // (GD, HD) layer base
    const float* __restrict__ hprev, int hstride,    // per-b element stride
    float* __restrict__ cstate,                      // (NB, HD)
    float* __restrict__ outh, int T, int t)          // h series (NB, T, HD)
{
    __shared__ float hs[NB][513];
    __shared__ float gl[8][33];
    const int tid = threadIdx.x;
    // stage h_{t-1} (32x512 fp32 = 64 KB) into LDS, +1-padded rows
    for (int p = 0; p < 16; ++p) {
        const int fi = (p * 256 + tid) << 2;
        const int b = fi >> 9, k = fi & 511;
        const float4 v = *(const float4*)(hprev + (size_t)b * hstride + k);
        hs[b][k] = v.x; hs[b][k + 1] = v.y; hs[b][k + 2] = v.z; hs[b][k + 3] = v.w;
    }
    __syncthreads();
    const int rl = tid >> 5;          // 0..7: gate*2 + jl
    const int b = tid & 31;
    const int gate = rl >> 1;
    const int jl = rl & 1;
    const int j = (blockIdx.x << 1) + jl;
    const int row = (gate << 9) + j;  // row in Whh / gate vector
    const float4* wp = (const float4*)(Whh + ((size_t)row << 9));
    float acc = 0.f;
#pragma unroll 8
    for (int k4 = 0; k4 < 128; ++k4) {
        const float4 w = wp[k4];      // broadcast across the 32 lanes of this row
        const int k = k4 << 2;
        acc = fmaf(w.x, hs[b][k], acc);
        acc = fmaf(w.y, hs[b][k + 1], acc);
        acc = fmaf(w.z, hs[b][k + 2], acc);
        acc = fmaf(w.w, hs[b][k + 3], acc);
    }
    acc += xgs[(size_t)b * xgb + row];  // xg already contains bih+bhh
    gl[rl][b] = acc;
    __syncthreads();
    if (tid < 64) {
        const int bb = tid & 31;
        const int jl2 = tid >> 5;
        const int jj = (blockIdx.x << 1) + jl2;
        const float gi = gl[0 + jl2][bb];
        const float gf = gl[2 + jl2][bb];
        const float gg = gl[4 + jl2][bb];
        const float go = gl[6 + jl2][bb];
        const size_t ci = ((size_t)bb << 9) + jj;
        const float c_new = sigf(gf) * cstate[ci] + sigf(gi) * tanhf_(gg);
        cstate[ci] = c_new;
        outh[(((size_t)bb * T + t) << 9) + jj] = sigf(go) * tanhf_(c_new);
    }
}

extern "C" void kernel_launch(void* const* d_in, const int* in_sizes, int n_in,
                              void* d_out, int out_size, void* d_ws, size_t ws_size,
                              hipStream_t stream)
{
    const float* x[3]   = {(const float*)d_in[0], (const float*)d_in[1],  (const float*)d_in[2]};
    const float* Wih[3] = {(const float*)d_in[3], (const float*)d_in[9],  (const float*)d_in[15]};
    const float* Whh[3] = {(const float*)d_in[4], (const float*)d_in[10], (const float*)d_in[16]};
    const float* bih[3] = {(const float*)d_in[5], (const float*)d_in[11], (const float*)d_in[17]};
    const float* bhh[3] = {(const float*)d_in[6], (const float*)d_in[12], (const float*)d_in[18]};
    const float* h0[3]  = {(const float*)d_in[7], (const float*)d_in[13], (const float*)d_in[19]};
    const float* c0[3]  = {(const float*)d_in[8], (const float*)d_in[14], (const float*)d_in[20]};
    const float* upW[2] = {(const float*)d_in[21], (const float*)d_in[23]};
    const float* upb[2] = {(const float*)d_in[22], (const float*)d_in[24]};

    float* ws = (float*)d_ws;
    float* bufA = ws;                               // 4M floats (tier-1 sized)
    float* bufB = ws + (size_t)NB * 256 * HD;       // 4M floats
    // choose xg chunk (timesteps) to fit workspace
    const size_t fixed = 2 * (size_t)NB * 256 * HD + (size_t)NB * HD;
    int Tc_cap = 256;
    while (Tc_cap > 32 && (fixed + (size_t)NB * Tc_cap * GD) * 4 > ws_size) Tc_cap >>= 1;
    float* xg  = ws + 2 * (size_t)NB * 256 * HD;    // NB*Tc_cap*GD floats
    float* cws = xg + (size_t)NB * Tc_cap * GD;     // NB*HD floats

    auto layer = [&](const float* in, float* out, int T, int tier, int l) {
        const float* WihL = Wih[tier] + (size_t)l * GD * HD;
        const float* WhhL = Whh[tier] + (size_t)l * GD * HD;
        const float* bihL = bih[tier] + (size_t)l * GD;
        const float* bhhL = bhh[tier] + (size_t)l * GD;
        hipMemcpyAsync(cws, c0[tier] + (size_t)l * NB * HD, (size_t)NB * HD * sizeof(float),
                       hipMemcpyDeviceToDevice, stream);
        const int Tc = T < Tc_cap ? T : Tc_cap;
        int tc_bits = 0; while ((1 << tc_bits) < Tc) ++tc_bits;
        for (int t0 = 0; t0 < T; t0 += Tc) {
            dim3 g((NB * Tc) / 64, GD / 64);
            gemm_xg<<<g, 256, 0, stream>>>(in, T, t0, tc_bits, WihL, bihL, bhhL, xg);
            for (int s = 0; s < Tc; ++s) {
                const int t = t0 + s;
                const float* hp; int hstride;
                if (t == 0) { hp = h0[tier] + (size_t)l * NB * HD; hstride = HD; }
                else        { hp = out + (size_t)(t - 1) * HD;     hstride = T * HD; }
                lstm_step<<<256, 256, 0, stream>>>(xg + (size_t)s * GD, Tc * GD,
                                                   WhhL, hp, hstride, cws, out, T, t);
            }
        }
    };

    float* dout = (float*)d_out;

    // Tier 0 (T=128)
    layer(x[0], bufA, 128, 0, 0);
    layer(bufA, bufB, 128, 0, 1);
    // Upsample 0: (B,128,512) -> (B,256,512), + x1 -> bufA
    {
        dim3 g((NB * 128) / 64, 1024 / 64);
        gemm_up<<<g, 256, 0, stream>>>(bufB, upW[0], 1024, upb[0], x[1], bufA, 7, 1);
    }
    // Tier 1 (T=256)
    layer(bufA, bufB, 256, 1, 0);
    layer(bufB, bufA, 256, 1, 1);
    // Upsample 1: (B,256,512) -> (B,2048,512), + x2 -> d_out (used as tier-2 activations)
    {
        dim3 g((NB * 256) / 64, 4096 / 64);
        gemm_up<<<g, 256, 0, stream>>>(bufA, upW[1], 4096, upb[1], x[2], dout, 8, 3);
    }
    // Tier 2 (T=2048), chunked in-place on d_out
    layer(dout, dout, 2048, 2, 0);
    layer(dout, dout, 2048, 2, 1);
}